// Round 1
// baseline (2254.052 us; speedup 1.0000x reference)
//
#include <hip/hip_runtime.h>
#include <cstdint>
#include <cstddef>

#define DD 256
constexpr int NDEV = 100;
constexpr int NCAT = 1000;
constexpr int NAPP = 100000;
constexpr int NE   = 100000;

// ---------------------------------------------------------------------------
// h[M,256] = relu(A[M,256] @ W[256,256] + b)
// fp32 tiled GEMM: 128x128 tile, BK=8, 256 threads, 8x8 per thread
// (split fragments ra/ra+64, ca/ca+64 to keep LDS reads <=2-way conflicted)
// ---------------------------------------------------------------------------
__global__ __launch_bounds__(256)
void linear_relu_kernel(const float* __restrict__ A, const float* __restrict__ W,
                        const float* __restrict__ bias, float* __restrict__ C,
                        int M) {
    __shared__ float As[8][128];   // transposed A tile: As[k][m]
    __shared__ float Bs[8][128];   // Bs[k][n]

    const int t  = threadIdx.x;
    const int m0 = blockIdx.x * 128;
    const int n0 = blockIdx.y * 128;
    const int ra = (t >> 4) << 2;   // 0,4,8,12 (per wave), rows ra..ra+3 and +64
    const int ca = (t & 15) << 2;   // 0..60,          cols ca..ca+3 and +64

    float acc[8][8];
#pragma unroll
    for (int i = 0; i < 8; ++i)
#pragma unroll
        for (int j = 0; j < 8; ++j) acc[i][j] = 0.f;

    for (int k0 = 0; k0 < DD; k0 += 8) {
        // stage A tile (transposed): thread t loads A[m0+t/2][k0+(t&1)*4 ..+3]
        {
            const int row = t >> 1;
            const int kk  = (t & 1) << 2;
            float4 v = make_float4(0.f, 0.f, 0.f, 0.f);
            if (m0 + row < M)
                v = *(const float4*)(A + (size_t)(m0 + row) * DD + k0 + kk);
            As[kk + 0][row] = v.x;
            As[kk + 1][row] = v.y;
            As[kk + 2][row] = v.z;
            As[kk + 3][row] = v.w;
        }
        // stage B tile: thread t loads W[k0+t/32][n0+(t&31)*4 ..+3]
        {
            const int kk = t >> 5;
            const int nn = (t & 31) << 2;
            *(float4*)&Bs[kk][nn] =
                *(const float4*)(W + (size_t)(k0 + kk) * DD + n0 + nn);
        }
        __syncthreads();
#pragma unroll
        for (int k = 0; k < 8; ++k) {
            const float4 a0 = *(const float4*)&As[k][ra];
            const float4 a1 = *(const float4*)&As[k][ra + 64];
            const float4 b0 = *(const float4*)&Bs[k][ca];
            const float4 b1 = *(const float4*)&Bs[k][ca + 64];
            const float av[8] = {a0.x, a0.y, a0.z, a0.w, a1.x, a1.y, a1.z, a1.w};
            const float bv[8] = {b0.x, b0.y, b0.z, b0.w, b1.x, b1.y, b1.z, b1.w};
#pragma unroll
            for (int i = 0; i < 8; ++i)
#pragma unroll
                for (int j = 0; j < 8; ++j)
                    acc[i][j] = fmaf(av[i], bv[j], acc[i][j]);
        }
        __syncthreads();
    }

    const float4 bias0 = *(const float4*)(bias + n0 + ca);
    const float4 bias1 = *(const float4*)(bias + n0 + ca + 64);
#pragma unroll
    for (int i = 0; i < 8; ++i) {
        const int row = m0 + ((i < 4) ? (ra + i) : (ra + 64 + i - 4));
        if (row >= M) continue;
        float4 o0, o1;
        o0.x = fmaxf(acc[i][0] + bias0.x, 0.f);
        o0.y = fmaxf(acc[i][1] + bias0.y, 0.f);
        o0.z = fmaxf(acc[i][2] + bias0.z, 0.f);
        o0.w = fmaxf(acc[i][3] + bias0.w, 0.f);
        o1.x = fmaxf(acc[i][4] + bias1.x, 0.f);
        o1.y = fmaxf(acc[i][5] + bias1.y, 0.f);
        o1.z = fmaxf(acc[i][6] + bias1.z, 0.f);
        o1.w = fmaxf(acc[i][7] + bias1.w, 0.f);
        *(float4*)(C + (size_t)row * DD + n0 + ca)      = o0;
        *(float4*)(C + (size_t)row * DD + n0 + ca + 64) = o1;
    }
}

// ---------------------------------------------------------------------------
// out[dst] += h[src] * w  for each edge. One wave (64 lanes) per edge,
// float4 gather per lane (1 KiB coalesced per edge), 4 scalar atomicAdds.
// ei layout: [2, nedge] (src row then dst row).
// ---------------------------------------------------------------------------
__global__ __launch_bounds__(256)
void scatter_kernel(const float* __restrict__ h, const int* __restrict__ ei,
                    const float* __restrict__ ew, float* __restrict__ out,
                    int nedge) {
    const int e    = (int)((blockIdx.x * blockDim.x + threadIdx.x) >> 6);
    const int lane = threadIdx.x & 63;
    if (e >= nedge) return;
    const int   src = ei[e];
    const int   dst = ei[nedge + e];
    const float w   = ew[e];
    const float4 v  = *(const float4*)(h + (size_t)src * DD + lane * 4);
    float* o = out + (size_t)dst * DD + lane * 4;
    atomicAdd(o + 0, v.x * w);
    atomicAdd(o + 1, v.y * w);
    atomicAdd(o + 2, v.z * w);
    atomicAdd(o + 3, v.w * w);
}

// h2_dev: layer-1 dev output is all-zero, so h2_dev row r = relu(b2_dev)
__global__ __launch_bounds__(256)
void bcast_bias_relu_kernel(const float* __restrict__ b, float* __restrict__ out,
                            int rows) {
    const int i = blockIdx.x * blockDim.x + threadIdx.x;
    if (i < rows * DD) out[i] = fmaxf(b[i & (DD - 1)], 0.f);
}

// ---------------------------------------------------------------------------
extern "C" void kernel_launch(void* const* d_in, const int* in_sizes, int n_in,
                              void* d_out, int out_size, void* d_ws, size_t ws_size,
                              hipStream_t stream) {
    const float* x_dev  = (const float*)d_in[0];
    // d_in[1] = x_cat: dead (no src=cat edges anywhere)
    const float* x_app  = (const float*)d_in[2];
    const int*   ei_da  = (const int*)d_in[3];
    const int*   ei_ac  = (const int*)d_in[4];
    const int*   ei_aa  = (const int*)d_in[5];
    const float* ew_da  = (const float*)d_in[6];
    const float* ew_ac  = (const float*)d_in[7];
    const float* ew_aa  = (const float*)d_in[8];
    const float* W1_dev = (const float*)d_in[9];
    const float* b1_dev = (const float*)d_in[10];
    // 11,12: W1_cat/b1_cat dead
    const float* W1_app = (const float*)d_in[13];
    const float* b1_app = (const float*)d_in[14];
    // 15: W2_dev dead (layer-1 dev output is zero)
    const float* b2_dev = (const float*)d_in[16];
    // 17,18: W2_cat/b2_cat dead
    const float* W2_app = (const float*)d_in[19];
    const float* b2_app = (const float*)d_in[20];

    float* out     = (float*)d_out;
    float* out_cat = out + (size_t)NDEV * DD;
    float* out_app = out + (size_t)(NDEV + NCAT) * DD;

    float* h_app = (float*)d_ws;                    // NAPP*DD f32 (h1, then h2)
    float* h_dev = h_app + (size_t)NAPP * DD;       // NDEV*DD f32

    // layer-1 app aggregation lives in the d_out app region (saves 100 MB ws)
    float* agg = out_app;

    const dim3 gApp((NAPP + 127) / 128, 2);
    const int  scatterGrid = (NE + 3) / 4;          // 4 waves (=edges) per block

    // ---- layer 1 ----
    hipMemsetAsync(agg, 0, (size_t)NAPP * DD * sizeof(float), stream);
    linear_relu_kernel<<<gApp, 256, 0, stream>>>(x_app, W1_app, b1_app, h_app, NAPP);
    linear_relu_kernel<<<dim3(1, 2), 256, 0, stream>>>(x_dev, W1_dev, b1_dev, h_dev, NDEV);
    scatter_kernel<<<scatterGrid, 256, 0, stream>>>(h_dev, ei_da, ew_da, agg, NE);
    scatter_kernel<<<scatterGrid, 256, 0, stream>>>(h_app, ei_aa, ew_aa, agg, NE);
    // (app->cat scatter of layer 1 is dead: nothing consumes layer-1 cat state)

    // ---- layer 2 ----
    linear_relu_kernel<<<gApp, 256, 0, stream>>>(agg, W2_app, b2_app, h_app, NAPP);
    bcast_bias_relu_kernel<<<(NDEV * DD + 255) / 256, 256, 0, stream>>>(b2_dev, h_dev, NDEV);

    hipMemsetAsync(d_out, 0, (size_t)out_size * sizeof(float), stream);
    scatter_kernel<<<scatterGrid, 256, 0, stream>>>(h_dev, ei_da, ew_da, out_app, NE);
    scatter_kernel<<<scatterGrid, 256, 0, stream>>>(h_app, ei_aa, ew_aa, out_app, NE);
    scatter_kernel<<<scatterGrid, 256, 0, stream>>>(h_app, ei_ac, ew_ac, out_cat, NE);
}

// Round 2
// 1225.889 us; speedup vs baseline: 1.8387x; 1.8387x over previous
//
#include <hip/hip_runtime.h>
#include <cstdint>
#include <cstddef>

#define DD 256
constexpr int NDEV = 100;
constexpr int NCAT = 1000;
constexpr int NAPP = 100000;
constexpr int NE   = 100000;

// ---------------------------------------------------------------------------
// h[M,256] = relu(A[M,256] @ W[256,256] + b)
// fp32 tiled GEMM: 128x128 tile, BK=8, 256 threads, 8x8 per thread
// ---------------------------------------------------------------------------
__global__ __launch_bounds__(256)
void linear_relu_kernel(const float* __restrict__ A, const float* __restrict__ W,
                        const float* __restrict__ bias, float* __restrict__ C,
                        int M) {
    __shared__ float As[8][128];   // transposed A tile: As[k][m]
    __shared__ float Bs[8][128];   // Bs[k][n]

    const int t  = threadIdx.x;
    const int m0 = blockIdx.x * 128;
    const int n0 = blockIdx.y * 128;
    const int ra = (t >> 4) << 2;
    const int ca = (t & 15) << 2;

    float acc[8][8];
#pragma unroll
    for (int i = 0; i < 8; ++i)
#pragma unroll
        for (int j = 0; j < 8; ++j) acc[i][j] = 0.f;

    for (int k0 = 0; k0 < DD; k0 += 8) {
        {
            const int row = t >> 1;
            const int kk  = (t & 1) << 2;
            float4 v = make_float4(0.f, 0.f, 0.f, 0.f);
            if (m0 + row < M)
                v = *(const float4*)(A + (size_t)(m0 + row) * DD + k0 + kk);
            As[kk + 0][row] = v.x;
            As[kk + 1][row] = v.y;
            As[kk + 2][row] = v.z;
            As[kk + 3][row] = v.w;
        }
        {
            const int kk = t >> 5;
            const int nn = (t & 31) << 2;
            *(float4*)&Bs[kk][nn] =
                *(const float4*)(W + (size_t)(k0 + kk) * DD + n0 + nn);
        }
        __syncthreads();
#pragma unroll
        for (int k = 0; k < 8; ++k) {
            const float4 a0 = *(const float4*)&As[k][ra];
            const float4 a1 = *(const float4*)&As[k][ra + 64];
            const float4 b0 = *(const float4*)&Bs[k][ca];
            const float4 b1 = *(const float4*)&Bs[k][ca + 64];
            const float av[8] = {a0.x, a0.y, a0.z, a0.w, a1.x, a1.y, a1.z, a1.w};
            const float bv[8] = {b0.x, b0.y, b0.z, b0.w, b1.x, b1.y, b1.z, b1.w};
#pragma unroll
            for (int i = 0; i < 8; ++i)
#pragma unroll
                for (int j = 0; j < 8; ++j)
                    acc[i][j] = fmaf(av[i], bv[j], acc[i][j]);
        }
        __syncthreads();
    }

    const float4 bias0 = *(const float4*)(bias + n0 + ca);
    const float4 bias1 = *(const float4*)(bias + n0 + ca + 64);
#pragma unroll
    for (int i = 0; i < 8; ++i) {
        const int row = m0 + ((i < 4) ? (ra + i) : (ra + 64 + i - 4));
        if (row >= M) continue;
        float4 o0, o1;
        o0.x = fmaxf(acc[i][0] + bias0.x, 0.f);
        o0.y = fmaxf(acc[i][1] + bias0.y, 0.f);
        o0.z = fmaxf(acc[i][2] + bias0.z, 0.f);
        o0.w = fmaxf(acc[i][3] + bias0.w, 0.f);
        o1.x = fmaxf(acc[i][4] + bias1.x, 0.f);
        o1.y = fmaxf(acc[i][5] + bias1.y, 0.f);
        o1.z = fmaxf(acc[i][6] + bias1.z, 0.f);
        o1.w = fmaxf(acc[i][7] + bias1.w, 0.f);
        *(float4*)(C + (size_t)row * DD + n0 + ca)      = o0;
        *(float4*)(C + (size_t)row * DD + n0 + ca + 64) = o1;
    }
}

// ---------------------------------------------------------------------------
// CSR build: histogram -> single-block scan (counts becomes cursor) -> fill
// ---------------------------------------------------------------------------
__global__ __launch_bounds__(256)
void hist_kernel(const int* __restrict__ dst, int* __restrict__ counts, int nedge) {
    const int e = blockIdx.x * 256 + threadIdx.x;
    if (e < nedge) atomicAdd(&counts[dst[e]], 1);
}

// exclusive scan of counts[0..n) into rs[0..n]; counts[i] overwritten with the
// same exclusive prefix (serves as the fill cursor).
__global__ __launch_bounds__(1024)
void scan_kernel(int* __restrict__ counts, int* __restrict__ rs, int n) {
    __shared__ int sd[1024];
    const int t = threadIdx.x;
    const int C = (n + 1023) >> 10;
    const int lo = t * C;
    const int hi = min(lo + C, n);
    int s = 0;
    for (int i = lo; i < hi; ++i) s += counts[i];
    sd[t] = s;
    __syncthreads();
    for (int off = 1; off < 1024; off <<= 1) {
        const int w = (t >= off) ? sd[t - off] : 0;
        __syncthreads();
        sd[t] += w;
        __syncthreads();
    }
    int run = sd[t] - s;  // exclusive prefix of this thread's chunk
    for (int i = lo; i < hi; ++i) {
        const int c = counts[i];
        rs[i] = run;
        counts[i] = run;   // cursor for fill
        run += c;
    }
    if (t == 1023) rs[n] = sd[1023];
}

// scatter edges into CSR order: srcs/wsorted indexed by slot
__global__ __launch_bounds__(256)
void fill_kernel(const int* __restrict__ ei, const float* __restrict__ ew,
                 int* __restrict__ cursor, int* __restrict__ srcs,
                 float* __restrict__ wsorted, int nedge) {
    const int e = blockIdx.x * 256 + threadIdx.x;
    if (e < nedge) {
        const int d   = ei[nedge + e];
        const int pos = atomicAdd(&cursor[d], 1);
        srcs[pos]    = ei[e];
        wsorted[pos] = ew[e];
    }
}

// ---------------------------------------------------------------------------
// Gather kernels: one wave (64 lanes) per destination row; float4 per lane.
// Every destination row is written exactly once (zeros if no edges).
// ---------------------------------------------------------------------------
__global__ __launch_bounds__(256)
void gather_l1_app_kernel(const float* __restrict__ hA, const float* __restrict__ hD,
                          const int* __restrict__ rsA, const int* __restrict__ sA,
                          const float* __restrict__ wA,
                          const int* __restrict__ rsD, const int* __restrict__ sD,
                          const float* __restrict__ wD,
                          float* __restrict__ out, int ndst) {
    const int d    = (int)((blockIdx.x * 256 + threadIdx.x) >> 6);
    const int lane = threadIdx.x & 63;
    if (d >= ndst) return;
    const int o = lane << 2;
    float4 acc = make_float4(0.f, 0.f, 0.f, 0.f);
    for (int p = rsA[d], pe = rsA[d + 1]; p < pe; ++p) {
        const float  w = wA[p];
        const float4 v = *(const float4*)(hA + (size_t)sA[p] * DD + o);
        acc.x = fmaf(w, v.x, acc.x);
        acc.y = fmaf(w, v.y, acc.y);
        acc.z = fmaf(w, v.z, acc.z);
        acc.w = fmaf(w, v.w, acc.w);
    }
    for (int p = rsD[d], pe = rsD[d + 1]; p < pe; ++p) {
        const float  w = wD[p];
        const float4 v = *(const float4*)(hD + (size_t)sD[p] * DD + o);
        acc.x = fmaf(w, v.x, acc.x);
        acc.y = fmaf(w, v.y, acc.y);
        acc.z = fmaf(w, v.z, acc.z);
        acc.w = fmaf(w, v.w, acc.w);
    }
    *(float4*)(out + (size_t)d * DD + o) = acc;
}

// layer 2 into app: aa gather from h2_app + (sum of da weights) * relu(b2_dev)
__global__ __launch_bounds__(256)
void gather_l2_app_kernel(const float* __restrict__ hA,
                          const int* __restrict__ rsA, const int* __restrict__ sA,
                          const float* __restrict__ wA,
                          const int* __restrict__ rsD, const float* __restrict__ wD,
                          const float* __restrict__ b2dev,
                          float* __restrict__ out, int ndst) {
    const int d    = (int)((blockIdx.x * 256 + threadIdx.x) >> 6);
    const int lane = threadIdx.x & 63;
    if (d >= ndst) return;
    const int o = lane << 2;
    float4 acc = make_float4(0.f, 0.f, 0.f, 0.f);
    for (int p = rsA[d], pe = rsA[d + 1]; p < pe; ++p) {
        const float  w = wA[p];
        const float4 v = *(const float4*)(hA + (size_t)sA[p] * DD + o);
        acc.x = fmaf(w, v.x, acc.x);
        acc.y = fmaf(w, v.y, acc.y);
        acc.z = fmaf(w, v.z, acc.z);
        acc.w = fmaf(w, v.w, acc.w);
    }
    float wsum = 0.f;
    for (int p = rsD[d], pe = rsD[d + 1]; p < pe; ++p) wsum += wD[p];
    const float4 b = *(const float4*)(b2dev + o);
    acc.x = fmaf(wsum, fmaxf(b.x, 0.f), acc.x);
    acc.y = fmaf(wsum, fmaxf(b.y, 0.f), acc.y);
    acc.z = fmaf(wsum, fmaxf(b.z, 0.f), acc.z);
    acc.w = fmaf(wsum, fmaxf(b.w, 0.f), acc.w);
    *(float4*)(out + (size_t)d * DD + o) = acc;
}

__global__ __launch_bounds__(256)
void gather_cat_kernel(const float* __restrict__ hA,
                       const int* __restrict__ rs, const int* __restrict__ s,
                       const float* __restrict__ w,
                       float* __restrict__ out, int ndst) {
    const int d    = (int)((blockIdx.x * 256 + threadIdx.x) >> 6);
    const int lane = threadIdx.x & 63;
    if (d >= ndst) return;
    const int o = lane << 2;
    float4 acc = make_float4(0.f, 0.f, 0.f, 0.f);
    for (int p = rs[d], pe = rs[d + 1]; p < pe; ++p) {
        const float  ww = w[p];
        const float4 v  = *(const float4*)(hA + (size_t)s[p] * DD + o);
        acc.x = fmaf(ww, v.x, acc.x);
        acc.y = fmaf(ww, v.y, acc.y);
        acc.z = fmaf(ww, v.z, acc.z);
        acc.w = fmaf(ww, v.w, acc.w);
    }
    *(float4*)(out + (size_t)d * DD + o) = acc;
}

// ---------------------------------------------------------------------------
extern "C" void kernel_launch(void* const* d_in, const int* in_sizes, int n_in,
                              void* d_out, int out_size, void* d_ws, size_t ws_size,
                              hipStream_t stream) {
    const float* x_dev  = (const float*)d_in[0];
    const float* x_app  = (const float*)d_in[2];
    const int*   ei_da  = (const int*)d_in[3];
    const int*   ei_ac  = (const int*)d_in[4];
    const int*   ei_aa  = (const int*)d_in[5];
    const float* ew_da  = (const float*)d_in[6];
    const float* ew_ac  = (const float*)d_in[7];
    const float* ew_aa  = (const float*)d_in[8];
    const float* W1_dev = (const float*)d_in[9];
    const float* b1_dev = (const float*)d_in[10];
    const float* W1_app = (const float*)d_in[13];
    const float* b1_app = (const float*)d_in[14];
    const float* b2_dev = (const float*)d_in[16];
    const float* W2_app = (const float*)d_in[19];
    const float* b2_app = (const float*)d_in[20];

    float* out     = (float*)d_out;
    float* out_cat = out + (size_t)NDEV * DD;
    float* out_app = out + (size_t)(NDEV + NCAT) * DD;

    // ---- workspace layout ----
    float* h_app = (float*)d_ws;                    // NAPP*DD
    float* h_dev = h_app + (size_t)NAPP * DD;       // NDEV*DD
    int*   counts = (int*)(h_dev + (size_t)NDEV * DD);  // NAPP (reused per type)
    int*   rs_aa  = counts + NAPP;                  // NAPP+1
    int*   s_aa   = rs_aa + NAPP + 1;               // NE
    float* w_aa   = (float*)(s_aa + NE);            // NE
    int*   rs_da  = (int*)(w_aa + NE);              // NAPP+1
    int*   s_da   = rs_da + NAPP + 1;               // NE
    float* w_da   = (float*)(s_da + NE);            // NE
    int*   rs_ac  = (int*)(w_da + NE);              // NCAT+1
    int*   s_ac   = rs_ac + NCAT + 1;               // NE
    float* w_ac   = (float*)(s_ac + NE);            // NE

    const int  egrid = (NE + 255) / 256;
    const dim3 gApp((NAPP + 127) / 128, 2);
    const int  gGatherApp = (NAPP + 3) / 4;   // 4 waves/block, wave per dst
    const int  gGatherCat = (NCAT + 3) / 4;

    // ---- CSR builds (3 edge types; counts buffer reused serially) ----
    hipMemsetAsync(counts, 0, (size_t)NAPP * sizeof(int), stream);
    hist_kernel<<<egrid, 256, 0, stream>>>(ei_aa + NE, counts, NE);
    scan_kernel<<<1, 1024, 0, stream>>>(counts, rs_aa, NAPP);
    fill_kernel<<<egrid, 256, 0, stream>>>(ei_aa, ew_aa, counts, s_aa, w_aa, NE);

    hipMemsetAsync(counts, 0, (size_t)NAPP * sizeof(int), stream);
    hist_kernel<<<egrid, 256, 0, stream>>>(ei_da + NE, counts, NE);
    scan_kernel<<<1, 1024, 0, stream>>>(counts, rs_da, NAPP);
    fill_kernel<<<egrid, 256, 0, stream>>>(ei_da, ew_da, counts, s_da, w_da, NE);

    hipMemsetAsync(counts, 0, (size_t)NCAT * sizeof(int), stream);
    hist_kernel<<<egrid, 256, 0, stream>>>(ei_ac + NE, counts, NE);
    scan_kernel<<<1, 1024, 0, stream>>>(counts, rs_ac, NCAT);
    fill_kernel<<<egrid, 256, 0, stream>>>(ei_ac, ew_ac, counts, s_ac, w_ac, NE);

    // ---- layer 1 ----
    linear_relu_kernel<<<gApp, 256, 0, stream>>>(x_app, W1_app, b1_app, h_app, NAPP);
    linear_relu_kernel<<<dim3(1, 2), 256, 0, stream>>>(x_dev, W1_dev, b1_dev, h_dev, NDEV);
    // agg (layer-1 app state) lives in the d_out app region
    gather_l1_app_kernel<<<gGatherApp, 256, 0, stream>>>(
        h_app, h_dev, rs_aa, s_aa, w_aa, rs_da, s_da, w_da, out_app, NAPP);

    // ---- layer 2 ----
    linear_relu_kernel<<<gApp, 256, 0, stream>>>(out_app, W2_app, b2_app, h_app, NAPP);
    gather_l2_app_kernel<<<gGatherApp, 256, 0, stream>>>(
        h_app, rs_aa, s_aa, w_aa, rs_da, w_da, b2_dev, out_app, NAPP);
    gather_cat_kernel<<<gGatherCat, 256, 0, stream>>>(
        h_app, rs_ac, s_ac, w_ac, out_cat, NCAT);

    // out_dev = 0 (no edges into dev)
    hipMemsetAsync(out, 0, (size_t)NDEV * DD * sizeof(float), stream);
}

// Round 3
// 780.782 us; speedup vs baseline: 2.8869x; 1.5701x over previous
//
#include <hip/hip_runtime.h>
#include <cstdint>
#include <cstddef>

#define DD 256
constexpr int NDEV = 100;
constexpr int NCAT = 1000;
constexpr int NAPP = 100000;
constexpr int NE   = 100000;
constexpr int NCNT = NAPP + NAPP + NCAT;   // concatenated counts: aa | da | ac

// ---------------------------------------------------------------------------
// h[M,256] = relu(A[M,256] @ W[256,256] + b)
// fp32 tiled GEMM: 128x128 tile, BK=8, 256 threads, 8x8 per thread
// ---------------------------------------------------------------------------
__global__ __launch_bounds__(256)
void linear_relu_kernel(const float* __restrict__ A, const float* __restrict__ W,
                        const float* __restrict__ bias, float* __restrict__ C,
                        int M) {
    __shared__ float As[8][128];   // transposed A tile: As[k][m]
    __shared__ float Bs[8][128];   // Bs[k][n]

    const int t  = threadIdx.x;
    const int m0 = blockIdx.x * 128;
    const int n0 = blockIdx.y * 128;
    const int ra = (t >> 4) << 2;
    const int ca = (t & 15) << 2;

    float acc[8][8];
#pragma unroll
    for (int i = 0; i < 8; ++i)
#pragma unroll
        for (int j = 0; j < 8; ++j) acc[i][j] = 0.f;

    for (int k0 = 0; k0 < DD; k0 += 8) {
        {
            const int row = t >> 1;
            const int kk  = (t & 1) << 2;
            float4 v = make_float4(0.f, 0.f, 0.f, 0.f);
            if (m0 + row < M)
                v = *(const float4*)(A + (size_t)(m0 + row) * DD + k0 + kk);
            As[kk + 0][row] = v.x;
            As[kk + 1][row] = v.y;
            As[kk + 2][row] = v.z;
            As[kk + 3][row] = v.w;
        }
        {
            const int kk = t >> 5;
            const int nn = (t & 31) << 2;
            *(float4*)&Bs[kk][nn] =
                *(const float4*)(W + (size_t)(k0 + kk) * DD + n0 + nn);
        }
        __syncthreads();
#pragma unroll
        for (int k = 0; k < 8; ++k) {
            const float4 a0 = *(const float4*)&As[k][ra];
            const float4 a1 = *(const float4*)&As[k][ra + 64];
            const float4 b0 = *(const float4*)&Bs[k][ca];
            const float4 b1 = *(const float4*)&Bs[k][ca + 64];
            const float av[8] = {a0.x, a0.y, a0.z, a0.w, a1.x, a1.y, a1.z, a1.w};
            const float bv[8] = {b0.x, b0.y, b0.z, b0.w, b1.x, b1.y, b1.z, b1.w};
#pragma unroll
            for (int i = 0; i < 8; ++i)
#pragma unroll
                for (int j = 0; j < 8; ++j)
                    acc[i][j] = fmaf(av[i], bv[j], acc[i][j]);
        }
        __syncthreads();
    }

    const float4 bias0 = *(const float4*)(bias + n0 + ca);
    const float4 bias1 = *(const float4*)(bias + n0 + ca + 64);
#pragma unroll
    for (int i = 0; i < 8; ++i) {
        const int row = m0 + ((i < 4) ? (ra + i) : (ra + 64 + i - 4));
        if (row >= M) continue;
        float4 o0, o1;
        o0.x = fmaxf(acc[i][0] + bias0.x, 0.f);
        o0.y = fmaxf(acc[i][1] + bias0.y, 0.f);
        o0.z = fmaxf(acc[i][2] + bias0.z, 0.f);
        o0.w = fmaxf(acc[i][3] + bias0.w, 0.f);
        o1.x = fmaxf(acc[i][4] + bias1.x, 0.f);
        o1.y = fmaxf(acc[i][5] + bias1.y, 0.f);
        o1.z = fmaxf(acc[i][6] + bias1.z, 0.f);
        o1.w = fmaxf(acc[i][7] + bias1.w, 0.f);
        *(float4*)(C + (size_t)row * DD + n0 + ca)      = o0;
        *(float4*)(C + (size_t)row * DD + n0 + ca + 64) = o1;
    }
}

// ---------------------------------------------------------------------------
// CSR build over CONCATENATED counts [aa(NAPP) | da(NAPP) | ac(NCAT)]
// hist3 -> scan_partial -> scan_bsum -> scan_apply -> fill3
// ---------------------------------------------------------------------------
__global__ __launch_bounds__(256)
void hist3_kernel(const int* __restrict__ d_aa, const int* __restrict__ d_da,
                  const int* __restrict__ d_ac, int* __restrict__ counts) {
    const int g = blockIdx.x * 256 + threadIdx.x;
    if (g < NE)            atomicAdd(&counts[d_aa[g]], 1);
    else if (g < 2 * NE)   atomicAdd(&counts[NAPP + d_da[g - NE]], 1);
    else if (g < 3 * NE)   atomicAdd(&counts[2 * NAPP + d_ac[g - 2 * NE]], 1);
}

// block b sums counts[b*1024 .. b*1024+1023] -> bsum[b]
__global__ __launch_bounds__(256)
void scan_partial_kernel(const int* __restrict__ counts, int* __restrict__ bsum,
                         int n) {
    __shared__ int sd[256];
    const int t   = threadIdx.x;
    const int idx = blockIdx.x * 1024 + t * 4;
    int s = 0;
    if (idx + 3 < n) {
        const int4 c = *(const int4*)(counts + idx);
        s = c.x + c.y + c.z + c.w;
    } else {
        for (int j = 0; j < 4; ++j) if (idx + j < n) s += counts[idx + j];
    }
    sd[t] = s;
    __syncthreads();
    for (int off = 128; off > 0; off >>= 1) {
        if (t < off) sd[t] += sd[t + off];
        __syncthreads();
    }
    if (t == 0) bsum[blockIdx.x] = sd[0];
}

// exclusive scan of bsum[0..nb) -> boff[0..nb), nb <= 256, one block
__global__ __launch_bounds__(256)
void scan_bsum_kernel(const int* __restrict__ bsum, int* __restrict__ boff, int nb) {
    __shared__ int sd[256];
    const int t = threadIdx.x;
    const int v = (t < nb) ? bsum[t] : 0;
    sd[t] = v;
    __syncthreads();
    for (int off = 1; off < 256; off <<= 1) {
        const int w = (t >= off) ? sd[t - off] : 0;
        __syncthreads();
        sd[t] += w;
        __syncthreads();
    }
    if (t < nb) boff[t] = sd[t] - v;
}

// exclusive prefix: rs[i] (and cursor[i]=counts[i] overwritten in place)
__global__ __launch_bounds__(256)
void scan_apply_kernel(int* __restrict__ counts, const int* __restrict__ boff,
                       int* __restrict__ rs, int n) {
    __shared__ int sd[256];
    const int t   = threadIdx.x;
    const int idx = blockIdx.x * 1024 + t * 4;
    int c[4] = {0, 0, 0, 0};
    if (idx + 3 < n) {
        const int4 v = *(const int4*)(counts + idx);
        c[0] = v.x; c[1] = v.y; c[2] = v.z; c[3] = v.w;
    } else {
        for (int j = 0; j < 4; ++j) if (idx + j < n) c[j] = counts[idx + j];
    }
    const int s = c[0] + c[1] + c[2] + c[3];
    sd[t] = s;
    __syncthreads();
    for (int off = 1; off < 256; off <<= 1) {
        const int w = (t >= off) ? sd[t - off] : 0;
        __syncthreads();
        sd[t] += w;
        __syncthreads();
    }
    int o = boff[blockIdx.x] + sd[t] - s;
#pragma unroll
    for (int j = 0; j < 4; ++j) {
        const int i = idx + j;
        if (i < n) {
            rs[i]     = o;
            counts[i] = o;     // becomes the fill cursor
            o += c[j];
            if (i == n - 1) rs[n] = o;
        }
    }
}

__global__ __launch_bounds__(256)
void fill3_kernel(const int* __restrict__ ei_aa, const float* __restrict__ ew_aa,
                  const int* __restrict__ ei_da, const float* __restrict__ ew_da,
                  const int* __restrict__ ei_ac, const float* __restrict__ ew_ac,
                  int* __restrict__ cursor, int* __restrict__ srcs,
                  float* __restrict__ wsorted) {
    const int g = blockIdx.x * 256 + threadIdx.x;
    if (g >= 3 * NE) return;
    const int*   ei;
    const float* ew;
    int e, base;
    if (g < NE)            { ei = ei_aa; ew = ew_aa; e = g;          base = 0; }
    else if (g < 2 * NE)   { ei = ei_da; ew = ew_da; e = g - NE;     base = NAPP; }
    else                   { ei = ei_ac; ew = ew_ac; e = g - 2 * NE; base = 2 * NAPP; }
    const int d   = ei[NE + e];
    const int pos = atomicAdd(&cursor[base + d], 1);
    srcs[pos]    = ei[e];
    wsorted[pos] = ew[e];
}

// ---------------------------------------------------------------------------
// Gather kernels: one wave (64 lanes) per destination row; float4 per lane.
// ---------------------------------------------------------------------------
__global__ __launch_bounds__(256)
void gather_l1_app_kernel(const float* __restrict__ hA, const float* __restrict__ hD,
                          const int* __restrict__ rsA, const int* __restrict__ rsD,
                          const int* __restrict__ s, const float* __restrict__ w,
                          float* __restrict__ out, int ndst) {
    const int d    = (int)((blockIdx.x * 256 + threadIdx.x) >> 6);
    const int lane = threadIdx.x & 63;
    if (d >= ndst) return;
    const int o = lane << 2;
    float4 acc = make_float4(0.f, 0.f, 0.f, 0.f);
    for (int p = rsA[d], pe = rsA[d + 1]; p < pe; ++p) {
        const float  ww = w[p];
        const float4 v  = *(const float4*)(hA + (size_t)s[p] * DD + o);
        acc.x = fmaf(ww, v.x, acc.x);
        acc.y = fmaf(ww, v.y, acc.y);
        acc.z = fmaf(ww, v.z, acc.z);
        acc.w = fmaf(ww, v.w, acc.w);
    }
    for (int p = rsD[d], pe = rsD[d + 1]; p < pe; ++p) {
        const float  ww = w[p];
        const float4 v  = *(const float4*)(hD + (size_t)s[p] * DD + o);
        acc.x = fmaf(ww, v.x, acc.x);
        acc.y = fmaf(ww, v.y, acc.y);
        acc.z = fmaf(ww, v.z, acc.z);
        acc.w = fmaf(ww, v.w, acc.w);
    }
    *(float4*)(out + (size_t)d * DD + o) = acc;
}

// layer 2 into app: aa gather from h2_app + (sum of da weights) * relu(b2_dev)
__global__ __launch_bounds__(256)
void gather_l2_app_kernel(const float* __restrict__ hA,
                          const int* __restrict__ rsA, const int* __restrict__ rsD,
                          const int* __restrict__ s, const float* __restrict__ w,
                          const float* __restrict__ b2dev,
                          float* __restrict__ out, int ndst) {
    const int d    = (int)((blockIdx.x * 256 + threadIdx.x) >> 6);
    const int lane = threadIdx.x & 63;
    if (d >= ndst) return;
    const int o = lane << 2;
    float4 acc = make_float4(0.f, 0.f, 0.f, 0.f);
    for (int p = rsA[d], pe = rsA[d + 1]; p < pe; ++p) {
        const float  ww = w[p];
        const float4 v  = *(const float4*)(hA + (size_t)s[p] * DD + o);
        acc.x = fmaf(ww, v.x, acc.x);
        acc.y = fmaf(ww, v.y, acc.y);
        acc.z = fmaf(ww, v.z, acc.z);
        acc.w = fmaf(ww, v.w, acc.w);
    }
    float wsum = 0.f;
    for (int p = rsD[d], pe = rsD[d + 1]; p < pe; ++p) wsum += w[p];
    const float4 b = *(const float4*)(b2dev + o);
    acc.x = fmaf(wsum, fmaxf(b.x, 0.f), acc.x);
    acc.y = fmaf(wsum, fmaxf(b.y, 0.f), acc.y);
    acc.z = fmaf(wsum, fmaxf(b.z, 0.f), acc.z);
    acc.w = fmaf(wsum, fmaxf(b.w, 0.f), acc.w);
    *(float4*)(out + (size_t)d * DD + o) = acc;
}

__global__ __launch_bounds__(256)
void gather_cat_kernel(const float* __restrict__ hA,
                       const int* __restrict__ rs, const int* __restrict__ s,
                       const float* __restrict__ w,
                       float* __restrict__ out, int ndst) {
    const int d    = (int)((blockIdx.x * 256 + threadIdx.x) >> 6);
    const int lane = threadIdx.x & 63;
    if (d >= ndst) return;
    const int o = lane << 2;
    float4 acc = make_float4(0.f, 0.f, 0.f, 0.f);
    for (int p = rs[d], pe = rs[d + 1]; p < pe; ++p) {
        const float  ww = w[p];
        const float4 v  = *(const float4*)(hA + (size_t)s[p] * DD + o);
        acc.x = fmaf(ww, v.x, acc.x);
        acc.y = fmaf(ww, v.y, acc.y);
        acc.z = fmaf(ww, v.z, acc.z);
        acc.w = fmaf(ww, v.w, acc.w);
    }
    *(float4*)(out + (size_t)d * DD + o) = acc;
}

// ---------------------------------------------------------------------------
extern "C" void kernel_launch(void* const* d_in, const int* in_sizes, int n_in,
                              void* d_out, int out_size, void* d_ws, size_t ws_size,
                              hipStream_t stream) {
    const float* x_dev  = (const float*)d_in[0];
    const float* x_app  = (const float*)d_in[2];
    const int*   ei_da  = (const int*)d_in[3];
    const int*   ei_ac  = (const int*)d_in[4];
    const int*   ei_aa  = (const int*)d_in[5];
    const float* ew_da  = (const float*)d_in[6];
    const float* ew_ac  = (const float*)d_in[7];
    const float* ew_aa  = (const float*)d_in[8];
    const float* W1_dev = (const float*)d_in[9];
    const float* b1_dev = (const float*)d_in[10];
    const float* W1_app = (const float*)d_in[13];
    const float* b1_app = (const float*)d_in[14];
    const float* b2_dev = (const float*)d_in[16];
    const float* W2_app = (const float*)d_in[19];
    const float* b2_app = (const float*)d_in[20];

    float* out     = (float*)d_out;
    float* out_cat = out + (size_t)NDEV * DD;
    float* out_app = out + (size_t)(NDEV + NCAT) * DD;

    // ---- workspace layout ----
    float* h_app  = (float*)d_ws;                       // NAPP*DD
    float* h_dev  = h_app + (size_t)NAPP * DD;          // NDEV*DD
    int*   counts = (int*)(h_dev + (size_t)NDEV * DD);  // NCNT (becomes cursor)
    int*   rs_all = counts + NCNT;                      // NCNT+1
    int*   s_all  = rs_all + NCNT + 1;                  // 3*NE
    float* w_all  = (float*)(s_all + 3 * NE);           // 3*NE
    int*   bsum   = (int*)(w_all + 3 * NE);             // <=256
    int*   boff   = bsum + 256;                         // <=256

    int* rs_aa = rs_all;               // [NAPP+1] (rs_aa[NAPP] = start of da ✓)
    int* rs_da = rs_all + NAPP;        // [NAPP+1]
    int* rs_ac = rs_all + 2 * NAPP;    // [NCAT+1]

    const int  nblk = (NCNT + 1023) / 1024;            // 197
    const dim3 gApp((NAPP + 127) / 128, 2);
    const int  gGatherApp = (NAPP + 3) / 4;
    const int  gGatherCat = (NCAT + 3) / 4;
    const int  g3e = (3 * NE + 255) / 256;

    // ---- CSR build (one concatenated scan) ----
    hipMemsetAsync(counts, 0, (size_t)NCNT * sizeof(int), stream);
    hist3_kernel<<<g3e, 256, 0, stream>>>(ei_aa + NE, ei_da + NE, ei_ac + NE, counts);
    scan_partial_kernel<<<nblk, 256, 0, stream>>>(counts, bsum, NCNT);
    scan_bsum_kernel<<<1, 256, 0, stream>>>(bsum, boff, nblk);
    scan_apply_kernel<<<nblk, 256, 0, stream>>>(counts, boff, rs_all, NCNT);
    fill3_kernel<<<g3e, 256, 0, stream>>>(ei_aa, ew_aa, ei_da, ew_da, ei_ac, ew_ac,
                                          counts, s_all, w_all);

    // ---- layer 1 ----
    linear_relu_kernel<<<gApp, 256, 0, stream>>>(x_app, W1_app, b1_app, h_app, NAPP);
    linear_relu_kernel<<<dim3(1, 2), 256, 0, stream>>>(x_dev, W1_dev, b1_dev, h_dev, NDEV);
    // layer-1 app aggregation lives in the d_out app region
    gather_l1_app_kernel<<<gGatherApp, 256, 0, stream>>>(
        h_app, h_dev, rs_aa, rs_da, s_all, w_all, out_app, NAPP);

    // ---- layer 2 ----
    linear_relu_kernel<<<gApp, 256, 0, stream>>>(out_app, W2_app, b2_app, h_app, NAPP);
    gather_l2_app_kernel<<<gGatherApp, 256, 0, stream>>>(
        h_app, rs_aa, rs_da, s_all, w_all, b2_dev, out_app, NAPP);
    gather_cat_kernel<<<gGatherCat, 256, 0, stream>>>(
        h_app, rs_ac, s_all, w_all, out_cat, NCAT);

    // out_dev = 0 (no edges into dev)
    hipMemsetAsync(out, 0, (size_t)NDEV * DD * sizeof(float), stream);
}

// Round 4
// 641.180 us; speedup vs baseline: 3.5155x; 1.2177x over previous
//
#include <hip/hip_runtime.h>
#include <cstdint>
#include <cstddef>

#define DD 256
constexpr int NDEV = 100;
constexpr int NCAT = 1000;
constexpr int NAPP = 100000;
constexpr int NE   = 100000;
constexpr int NCNT = NAPP + NAPP + NCAT;   // concatenated counts: aa | da | ac

typedef __attribute__((ext_vector_type(8))) short  bf16x8;
typedef __attribute__((ext_vector_type(8))) unsigned short ushort8;
typedef __attribute__((ext_vector_type(4))) float  f32x4;

// ---- fp32 <-> bf16 split helpers -----------------------------------------
__device__ __forceinline__ unsigned short f2bf(float f) {
    unsigned int u = __float_as_uint(f);
    u += 0x7fffu + ((u >> 16) & 1u);        // round-to-nearest-even
    return (unsigned short)(u >> 16);
}
__device__ __forceinline__ float bf2f(unsigned short h) {
    return __uint_as_float((unsigned int)h << 16);
}

// ---------------------------------------------------------------------------
// W split+transpose: W[k][n] fp32 -> Wt_hi/lo[n][k] bf16.  grid 256 x 256thr
// ---------------------------------------------------------------------------
__global__ __launch_bounds__(256)
void wsplit_kernel(const float* __restrict__ W, unsigned short* __restrict__ hi,
                   unsigned short* __restrict__ lo) {
    const int idx = blockIdx.x * 256 + threadIdx.x;   // 0..65535
    const int k = idx >> 8, n = idx & 255;
    const float f = W[idx];                            // coalesced
    const unsigned short h = f2bf(f);
    hi[n * 256 + k] = h;
    lo[n * 256 + k] = f2bf(f - bf2f(h));
}

// ---------------------------------------------------------------------------
// h[M,256] = relu(A[M,256] @ W[256,256] + b) via split-bf16 MFMA.
// 4 waves; wave w owns cols [64w,64w+64); 8x4 frags of 16x16x32.
// A tile 128xBK(32) converted to hi/lo bf16 in staging; Wt pre-split [n][k].
// ---------------------------------------------------------------------------
#define BK 32
#define PAD 40   // LDS row stride in elements (32+8): bank-uniform for b128

__global__ __launch_bounds__(256, 2)
void linear_relu_mfma_kernel(const float* __restrict__ A,
                             const unsigned short* __restrict__ Wt_hi,
                             const unsigned short* __restrict__ Wt_lo,
                             const float* __restrict__ bias,
                             float* __restrict__ C, int M) {
    __shared__ unsigned short As_hi[128][PAD];
    __shared__ unsigned short As_lo[128][PAD];
    __shared__ unsigned short Ws_hi[256][PAD];
    __shared__ unsigned short Ws_lo[256][PAD];

    const int t    = threadIdx.x;
    const int wave = t >> 6;
    const int lane = t & 63;
    const int cl   = lane & 15;          // frag row/col within 16
    const int kg8  = (lane >> 4) * 8;    // k-group offset (8 bf16)
    const int m0   = blockIdx.x * 128;
    const int n0w  = wave * 64;

    f32x4 acc[8][4];
#pragma unroll
    for (int m = 0; m < 8; ++m)
#pragma unroll
        for (int n = 0; n < 4; ++n) acc[m][n] = (f32x4){0.f, 0.f, 0.f, 0.f};

    const int ar = t >> 1;               // A staging row 0..127
    const int ak = (t & 1) * 16;         // A staging k-base (16 floats)

    for (int k0 = 0; k0 < DD; k0 += BK) {
        // ---- stage A (fp32 -> hi/lo bf16) ----
        {
            float fv[16];
            if (m0 + ar < M) {
                const float* p = A + (size_t)(m0 + ar) * DD + k0 + ak;
#pragma unroll
                for (int i = 0; i < 4; ++i) {
                    const float4 v = *(const float4*)(p + i * 4);
                    fv[i * 4 + 0] = v.x; fv[i * 4 + 1] = v.y;
                    fv[i * 4 + 2] = v.z; fv[i * 4 + 3] = v.w;
                }
            } else {
#pragma unroll
                for (int i = 0; i < 16; ++i) fv[i] = 0.f;
            }
#pragma unroll
            for (int g = 0; g < 2; ++g) {
                ushort8 hh, ll;
#pragma unroll
                for (int j = 0; j < 8; ++j) {
                    const float f = fv[g * 8 + j];
                    const unsigned short h = f2bf(f);
                    hh[j] = h;
                    ll[j] = f2bf(f - bf2f(h));
                }
                *(ushort8*)&As_hi[ar][ak + g * 8] = hh;
                *(ushort8*)&As_lo[ar][ak + g * 8] = ll;
            }
        }
        // ---- stage W (pre-split bf16, [n][k] layout) ----
        {
            const unsigned short* ph = Wt_hi + (size_t)t * DD + k0;
            const unsigned short* pl = Wt_lo + (size_t)t * DD + k0;
#pragma unroll
            for (int g = 0; g < 4; ++g) {
                *(ushort8*)&Ws_hi[t][g * 8] = *(const ushort8*)(ph + g * 8);
                *(ushort8*)&Ws_lo[t][g * 8] = *(const ushort8*)(pl + g * 8);
            }
        }
        __syncthreads();

        // ---- MFMA: acc += Ah*Wh + Al*Wh + Ah*Wl ----
        bf16x8 ah[8], al[8], bb[4];
#pragma unroll
        for (int m = 0; m < 8; ++m) {
            ah[m] = *(const bf16x8*)&As_hi[m * 16 + cl][kg8];
            al[m] = *(const bf16x8*)&As_lo[m * 16 + cl][kg8];
        }
#pragma unroll
        for (int n = 0; n < 4; ++n)
            bb[n] = *(const bf16x8*)&Ws_hi[n0w + n * 16 + cl][kg8];
#pragma unroll
        for (int m = 0; m < 8; ++m)
#pragma unroll
            for (int n = 0; n < 4; ++n)
                acc[m][n] = __builtin_amdgcn_mfma_f32_16x16x32_bf16(
                    ah[m], bb[n], acc[m][n], 0, 0, 0);
#pragma unroll
        for (int m = 0; m < 8; ++m)
#pragma unroll
            for (int n = 0; n < 4; ++n)
                acc[m][n] = __builtin_amdgcn_mfma_f32_16x16x32_bf16(
                    al[m], bb[n], acc[m][n], 0, 0, 0);
#pragma unroll
        for (int n = 0; n < 4; ++n)
            bb[n] = *(const bf16x8*)&Ws_lo[n0w + n * 16 + cl][kg8];
#pragma unroll
        for (int m = 0; m < 8; ++m)
#pragma unroll
            for (int n = 0; n < 4; ++n)
                acc[m][n] = __builtin_amdgcn_mfma_f32_16x16x32_bf16(
                    ah[m], bb[n], acc[m][n], 0, 0, 0);
        __syncthreads();
    }

    // ---- epilogue: bias + relu, C/D layout col=lane&15, row=(lane>>4)*4+j ----
    const int r4 = (lane >> 4) << 2;
#pragma unroll
    for (int n = 0; n < 4; ++n) {
        const int col = n0w + n * 16 + cl;
        const float bv = bias[col];
#pragma unroll
        for (int m = 0; m < 8; ++m) {
            const int rowb = m0 + m * 16 + r4;
            float* cp = C + (size_t)rowb * DD + col;
#pragma unroll
            for (int j = 0; j < 4; ++j)
                if (rowb + j < M) cp[(size_t)j * DD] = fmaxf(acc[m][n][j] + bv, 0.f);
        }
    }
}

// ---------------------------------------------------------------------------
// fp32 GEMM for the tiny dev transform (M=100)
// ---------------------------------------------------------------------------
__global__ __launch_bounds__(256)
void linear_relu_kernel(const float* __restrict__ A, const float* __restrict__ W,
                        const float* __restrict__ bias, float* __restrict__ C,
                        int M) {
    __shared__ float As[8][128];
    __shared__ float Bs[8][128];

    const int t  = threadIdx.x;
    const int m0 = blockIdx.x * 128;
    const int n0 = blockIdx.y * 128;
    const int ra = (t >> 4) << 2;
    const int ca = (t & 15) << 2;

    float acc[8][8];
#pragma unroll
    for (int i = 0; i < 8; ++i)
#pragma unroll
        for (int j = 0; j < 8; ++j) acc[i][j] = 0.f;

    for (int k0 = 0; k0 < DD; k0 += 8) {
        {
            const int row = t >> 1;
            const int kk  = (t & 1) << 2;
            float4 v = make_float4(0.f, 0.f, 0.f, 0.f);
            if (m0 + row < M)
                v = *(const float4*)(A + (size_t)(m0 + row) * DD + k0 + kk);
            As[kk + 0][row] = v.x;
            As[kk + 1][row] = v.y;
            As[kk + 2][row] = v.z;
            As[kk + 3][row] = v.w;
        }
        {
            const int kk = t >> 5;
            const int nn = (t & 31) << 2;
            *(float4*)&Bs[kk][nn] =
                *(const float4*)(W + (size_t)(k0 + kk) * DD + n0 + nn);
        }
        __syncthreads();
#pragma unroll
        for (int k = 0; k < 8; ++k) {
            const float4 a0 = *(const float4*)&As[k][ra];
            const float4 a1 = *(const float4*)&As[k][ra + 64];
            const float4 b0 = *(const float4*)&Bs[k][ca];
            const float4 b1 = *(const float4*)&Bs[k][ca + 64];
            const float av[8] = {a0.x, a0.y, a0.z, a0.w, a1.x, a1.y, a1.z, a1.w};
            const float bv[8] = {b0.x, b0.y, b0.z, b0.w, b1.x, b1.y, b1.z, b1.w};
#pragma unroll
            for (int i = 0; i < 8; ++i)
#pragma unroll
                for (int j = 0; j < 8; ++j)
                    acc[i][j] = fmaf(av[i], bv[j], acc[i][j]);
        }
        __syncthreads();
    }

    const float4 bias0 = *(const float4*)(bias + n0 + ca);
    const float4 bias1 = *(const float4*)(bias + n0 + ca + 64);
#pragma unroll
    for (int i = 0; i < 8; ++i) {
        const int row = m0 + ((i < 4) ? (ra + i) : (ra + 64 + i - 4));
        if (row >= M) continue;
        float4 o0, o1;
        o0.x = fmaxf(acc[i][0] + bias0.x, 0.f);
        o0.y = fmaxf(acc[i][1] + bias0.y, 0.f);
        o0.z = fmaxf(acc[i][2] + bias0.z, 0.f);
        o0.w = fmaxf(acc[i][3] + bias0.w, 0.f);
        o1.x = fmaxf(acc[i][4] + bias1.x, 0.f);
        o1.y = fmaxf(acc[i][5] + bias1.y, 0.f);
        o1.z = fmaxf(acc[i][6] + bias1.z, 0.f);
        o1.w = fmaxf(acc[i][7] + bias1.w, 0.f);
        *(float4*)(C + (size_t)row * DD + n0 + ca)      = o0;
        *(float4*)(C + (size_t)row * DD + n0 + ca + 64) = o1;
    }
}

// ---------------------------------------------------------------------------
// CSR build over CONCATENATED counts [aa(NAPP) | da(NAPP) | ac(NCAT)]
// ---------------------------------------------------------------------------
__global__ __launch_bounds__(256)
void hist3_kernel(const int* __restrict__ d_aa, const int* __restrict__ d_da,
                  const int* __restrict__ d_ac, int* __restrict__ counts) {
    const int g = blockIdx.x * 256 + threadIdx.x;
    if (g < NE)            atomicAdd(&counts[d_aa[g]], 1);
    else if (g < 2 * NE)   atomicAdd(&counts[NAPP + d_da[g - NE]], 1);
    else if (g < 3 * NE)   atomicAdd(&counts[2 * NAPP + d_ac[g - 2 * NE]], 1);
}

__global__ __launch_bounds__(256)
void scan_partial_kernel(const int* __restrict__ counts, int* __restrict__ bsum,
                         int n) {
    __shared__ int sd[256];
    const int t   = threadIdx.x;
    const int idx = blockIdx.x * 1024 + t * 4;
    int s = 0;
    if (idx + 3 < n) {
        const int4 c = *(const int4*)(counts + idx);
        s = c.x + c.y + c.z + c.w;
    } else {
        for (int j = 0; j < 4; ++j) if (idx + j < n) s += counts[idx + j];
    }
    sd[t] = s;
    __syncthreads();
    for (int off = 128; off > 0; off >>= 1) {
        if (t < off) sd[t] += sd[t + off];
        __syncthreads();
    }
    if (t == 0) bsum[blockIdx.x] = sd[0];
}

__global__ __launch_bounds__(256)
void scan_bsum_kernel(const int* __restrict__ bsum, int* __restrict__ boff, int nb) {
    __shared__ int sd[256];
    const int t = threadIdx.x;
    const int v = (t < nb) ? bsum[t] : 0;
    sd[t] = v;
    __syncthreads();
    for (int off = 1; off < 256; off <<= 1) {
        const int w = (t >= off) ? sd[t - off] : 0;
        __syncthreads();
        sd[t] += w;
        __syncthreads();
    }
    if (t < nb) boff[t] = sd[t] - v;
}

__global__ __launch_bounds__(256)
void scan_apply_kernel(int* __restrict__ counts, const int* __restrict__ boff,
                       int* __restrict__ rs, int n) {
    __shared__ int sd[256];
    const int t   = threadIdx.x;
    const int idx = blockIdx.x * 1024 + t * 4;
    int c[4] = {0, 0, 0, 0};
    if (idx + 3 < n) {
        const int4 v = *(const int4*)(counts + idx);
        c[0] = v.x; c[1] = v.y; c[2] = v.z; c[3] = v.w;
    } else {
        for (int j = 0; j < 4; ++j) if (idx + j < n) c[j] = counts[idx + j];
    }
    const int s = c[0] + c[1] + c[2] + c[3];
    sd[t] = s;
    __syncthreads();
    for (int off = 1; off < 256; off <<= 1) {
        const int w = (t >= off) ? sd[t - off] : 0;
        __syncthreads();
        sd[t] += w;
        __syncthreads();
    }
    int o = boff[blockIdx.x] + sd[t] - s;
#pragma unroll
    for (int j = 0; j < 4; ++j) {
        const int i = idx + j;
        if (i < n) {
            rs[i]     = o;
            counts[i] = o;
            o += c[j];
            if (i == n - 1) rs[n] = o;
        }
    }
}

__global__ __launch_bounds__(256)
void fill3_kernel(const int* __restrict__ ei_aa, const float* __restrict__ ew_aa,
                  const int* __restrict__ ei_da, const float* __restrict__ ew_da,
                  const int* __restrict__ ei_ac, const float* __restrict__ ew_ac,
                  int* __restrict__ cursor, int* __restrict__ srcs,
                  float* __restrict__ wsorted) {
    const int g = blockIdx.x * 256 + threadIdx.x;
    if (g >= 3 * NE) return;
    const int*   ei;
    const float* ew;
    int e, base;
    if (g < NE)            { ei = ei_aa; ew = ew_aa; e = g;          base = 0; }
    else if (g < 2 * NE)   { ei = ei_da; ew = ew_da; e = g - NE;     base = NAPP; }
    else                   { ei = ei_ac; ew = ew_ac; e = g - 2 * NE; base = 2 * NAPP; }
    const int d   = ei[NE + e];
    const int pos = atomicAdd(&cursor[base + d], 1);
    srcs[pos]    = ei[e];
    wsorted[pos] = ew[e];
}

// ---------------------------------------------------------------------------
// Gather kernels: one wave per destination row; float4 per lane.
// ---------------------------------------------------------------------------
__global__ __launch_bounds__(256)
void gather_l1_app_kernel(const float* __restrict__ hA, const float* __restrict__ hD,
                          const int* __restrict__ rsA, const int* __restrict__ rsD,
                          const int* __restrict__ s, const float* __restrict__ w,
                          float* __restrict__ out, int ndst) {
    const int d    = (int)((blockIdx.x * 256 + threadIdx.x) >> 6);
    const int lane = threadIdx.x & 63;
    if (d >= ndst) return;
    const int o = lane << 2;
    float4 acc = make_float4(0.f, 0.f, 0.f, 0.f);
    for (int p = rsA[d], pe = rsA[d + 1]; p < pe; ++p) {
        const float  ww = w[p];
        const float4 v  = *(const float4*)(hA + (size_t)s[p] * DD + o);
        acc.x = fmaf(ww, v.x, acc.x);
        acc.y = fmaf(ww, v.y, acc.y);
        acc.z = fmaf(ww, v.z, acc.z);
        acc.w = fmaf(ww, v.w, acc.w);
    }
    for (int p = rsD[d], pe = rsD[d + 1]; p < pe; ++p) {
        const float  ww = w[p];
        const float4 v  = *(const float4*)(hD + (size_t)s[p] * DD + o);
        acc.x = fmaf(ww, v.x, acc.x);
        acc.y = fmaf(ww, v.y, acc.y);
        acc.z = fmaf(ww, v.z, acc.z);
        acc.w = fmaf(ww, v.w, acc.w);
    }
    *(float4*)(out + (size_t)d * DD + o) = acc;
}

__global__ __launch_bounds__(256)
void gather_l2_app_kernel(const float* __restrict__ hA,
                          const int* __restrict__ rsA, const int* __restrict__ rsD,
                          const int* __restrict__ s, const float* __restrict__ w,
                          const float* __restrict__ b2dev,
                          float* __restrict__ out, int ndst) {
    const int d    = (int)((blockIdx.x * 256 + threadIdx.x) >> 6);
    const int lane = threadIdx.x & 63;
    if (d >= ndst) return;
    const int o = lane << 2;
    float4 acc = make_float4(0.f, 0.f, 0.f, 0.f);
    for (int p = rsA[d], pe = rsA[d + 1]; p < pe; ++p) {
        const float  ww = w[p];
        const float4 v  = *(const float4*)(hA + (size_t)s[p] * DD + o);
        acc.x = fmaf(ww, v.x, acc.x);
        acc.y = fmaf(ww, v.y, acc.y);
        acc.z = fmaf(ww, v.z, acc.z);
        acc.w = fmaf(ww, v.w, acc.w);
    }
    float wsum = 0.f;
    for (int p = rsD[d], pe = rsD[d + 1]; p < pe; ++p) wsum += w[p];
    const float4 b = *(const float4*)(b2dev + o);
    acc.x = fmaf(wsum, fmaxf(b.x, 0.f), acc.x);
    acc.y = fmaf(wsum, fmaxf(b.y, 0.f), acc.y);
    acc.z = fmaf(wsum, fmaxf(b.z, 0.f), acc.z);
    acc.w = fmaf(wsum, fmaxf(b.w, 0.f), acc.w);
    *(float4*)(out + (size_t)d * DD + o) = acc;
}

__global__ __launch_bounds__(256)
void gather_cat_kernel(const float* __restrict__ hA,
                       const int* __restrict__ rs, const int* __restrict__ s,
                       const float* __restrict__ w,
                       float* __restrict__ out, int ndst) {
    const int d    = (int)((blockIdx.x * 256 + threadIdx.x) >> 6);
    const int lane = threadIdx.x & 63;
    if (d >= ndst) return;
    const int o = lane << 2;
    float4 acc = make_float4(0.f, 0.f, 0.f, 0.f);
    for (int p = rs[d], pe = rs[d + 1]; p < pe; ++p) {
        const float  ww = w[p];
        const float4 v  = *(const float4*)(hA + (size_t)s[p] * DD + o);
        acc.x = fmaf(ww, v.x, acc.x);
        acc.y = fmaf(ww, v.y, acc.y);
        acc.z = fmaf(ww, v.z, acc.z);
        acc.w = fmaf(ww, v.w, acc.w);
    }
    *(float4*)(out + (size_t)d * DD + o) = acc;
}

// ---------------------------------------------------------------------------
extern "C" void kernel_launch(void* const* d_in, const int* in_sizes, int n_in,
                              void* d_out, int out_size, void* d_ws, size_t ws_size,
                              hipStream_t stream) {
    const float* x_dev  = (const float*)d_in[0];
    const float* x_app  = (const float*)d_in[2];
    const int*   ei_da  = (const int*)d_in[3];
    const int*   ei_ac  = (const int*)d_in[4];
    const int*   ei_aa  = (const int*)d_in[5];
    const float* ew_da  = (const float*)d_in[6];
    const float* ew_ac  = (const float*)d_in[7];
    const float* ew_aa  = (const float*)d_in[8];
    const float* W1_dev = (const float*)d_in[9];
    const float* b1_dev = (const float*)d_in[10];
    const float* W1_app = (const float*)d_in[13];
    const float* b1_app = (const float*)d_in[14];
    const float* b2_dev = (const float*)d_in[16];
    const float* W2_app = (const float*)d_in[19];
    const float* b2_app = (const float*)d_in[20];

    float* out     = (float*)d_out;
    float* out_cat = out + (size_t)NDEV * DD;
    float* out_app = out + (size_t)(NDEV + NCAT) * DD;

    // ---- workspace layout ----
    float* h_app  = (float*)d_ws;                       // NAPP*DD
    float* h_dev  = h_app + (size_t)NAPP * DD;          // NDEV*DD
    int*   counts = (int*)(h_dev + (size_t)NDEV * DD);  // NCNT (cursor; reused
                                                        //  as Wt after fill3)
    int*   rs_all = counts + NCNT;                      // NCNT+1
    int*   s_all  = rs_all + NCNT + 1;                  // 3*NE
    float* w_all  = (float*)(s_all + 3 * NE);           // 3*NE
    int*   bsum   = (int*)(w_all + 3 * NE);             // <=256
    int*   boff   = bsum + 256;                         // <=256

    int* rs_aa = rs_all;
    int* rs_da = rs_all + NAPP;
    int* rs_ac = rs_all + 2 * NAPP;

    // Wt arrays reuse the cursor region (dead after fill3): 4 x 64K ushort
    unsigned short* wt1_hi = (unsigned short*)counts;
    unsigned short* wt1_lo = wt1_hi + 65536;
    unsigned short* wt2_hi = wt1_lo + 65536;
    unsigned short* wt2_lo = wt2_hi + 65536;

    const int  nblk = (NCNT + 1023) / 1024;
    const int  gMfma = (NAPP + 127) / 128;
    const int  gGatherApp = (NAPP + 3) / 4;
    const int  gGatherCat = (NCAT + 3) / 4;
    const int  g3e = (3 * NE + 255) / 256;

    // ---- CSR build first (cursor region is reused for Wt afterwards) ----
    hipMemsetAsync(counts, 0, (size_t)NCNT * sizeof(int), stream);
    hist3_kernel<<<g3e, 256, 0, stream>>>(ei_aa + NE, ei_da + NE, ei_ac + NE, counts);
    scan_partial_kernel<<<nblk, 256, 0, stream>>>(counts, bsum, NCNT);
    scan_bsum_kernel<<<1, 256, 0, stream>>>(bsum, boff, nblk);
    scan_apply_kernel<<<nblk, 256, 0, stream>>>(counts, boff, rs_all, NCNT);
    fill3_kernel<<<g3e, 256, 0, stream>>>(ei_aa, ew_aa, ei_da, ew_da, ei_ac, ew_ac,
                                          counts, s_all, w_all);

    // ---- weight split/transpose (cursor region now dead) ----
    wsplit_kernel<<<256, 256, 0, stream>>>(W1_app, wt1_hi, wt1_lo);
    wsplit_kernel<<<256, 256, 0, stream>>>(W2_app, wt2_hi, wt2_lo);

    // ---- layer 1 ----
    linear_relu_mfma_kernel<<<gMfma, 256, 0, stream>>>(x_app, wt1_hi, wt1_lo,
                                                       b1_app, h_app, NAPP);
    linear_relu_kernel<<<dim3(1, 2), 256, 0, stream>>>(x_dev, W1_dev, b1_dev,
                                                       h_dev, NDEV);
    gather_l1_app_kernel<<<gGatherApp, 256, 0, stream>>>(
        h_app, h_dev, rs_aa, rs_da, s_all, w_all, out_app, NAPP);

    // ---- layer 2 ----
    linear_relu_mfma_kernel<<<gMfma, 256, 0, stream>>>(out_app, wt2_hi, wt2_lo,
                                                       b2_app, h_app, NAPP);
    gather_l2_app_kernel<<<gGatherApp, 256, 0, stream>>>(
        h_app, rs_aa, rs_da, s_all, w_all, b2_dev, out_app, NAPP);
    gather_cat_kernel<<<gGatherCat, 256, 0, stream>>>(
        h_app, rs_ac, s_all, w_all, out_cat, NCAT);

    // out_dev = 0 (no edges into dev)
    hipMemsetAsync(out, 0, (size_t)NDEV * DD * sizeof(float), stream);
}